// Round 5
// baseline (167.036 us; speedup 1.0000x reference)
//
#include <hip/hip_runtime.h>
#include <math.h>

#define BATCH  32
#define CH     3
#define H      512
#define W      512
#define KWIN   15
#define PAD    7
#define TB     64                 // output rows per BLOCK (4 waves x 16 rows)
#define NCHK   10                 // 10 chunks x 8 rows = 80 staged (78 used)
#define STRIP  112                // output cols per block (frame = 128)
#define NSTRIP 5
#define NBLK   (BATCH * (H / TB) * NSTRIP)   // 1280
#define SLOT_F (8 * 3 * 128)      // floats per LDS slot (8 rows x 3 ch x 128 cols)

static __device__ __forceinline__ float2 min2(float2 a, float2 b) {
    float2 r;
    r.x = fminf(a.x, b.x);
    r.y = fminf(a.y, b.y);
    return r;
}

// R20: switch the streaming-load MECHANISM. Ledger: depth/occupancy/instr-
// count/issued-bytes/XCD-swizzle all neutral at ~55 us = 2.7 TB/s delivered
// (~4 KB in flight per CU ~= 30 x 128B lines) -> per-CU outstanding-miss cap
// on the VGPR-return load path is the last consistent theory. This kernel
// streams input via __builtin_amdgcn_global_load_lds (DMA to LDS, vmcnt-
// counted, no VGPR writeback, up to 63 outstanding): 4-slot circular LDS
// buffer, 8-row chunks, width-16, prefetch distance 2, counted
// s_waitcnt vmcnt(6) + raw s_barrier (m201 pattern; never drain mid-loop).
// Consume: in-order van Herk (15-row reg ring -> suffix mins -> prefix
// stream), all reg indices static; stores deferred to obuf so vmcnt counts
// loads only.
// Falsified (do not retry): b128 bytes/slot (R17), LDS h-min staging bytes
// cut (R18), XCD swizzle (R19), DEPTH/TLP scaling, __launch_bounds__,
// global two-pass, dynamic reg indexing.
__global__ void dcp_dma1(const float* __restrict__ I, float* __restrict__ out) {
    __shared__ float raw[4 * SLOT_F];                 // 48 KB -> 3 blocks/CU

    const int w   = threadIdx.x >> 6;                 // wave 0..3
    const int L   = threadIdx.x & 63;
    const int bid = blockIdx.x;
    const int s   = bid % NSTRIP;
    const int rg  = (bid / NSTRIP) % (H / TB);
    const int b   = bid / (NSTRIP * (H / TB));
    const int Y0  = rg * TB;

    // stage geometry: lanes 0-31 = pair 2m (row,ch), lanes 32-63 = pair 2m+1
    const int q    = L & 31;                          // lane within half
    const int g    = L >> 5;                          // half index
    const int gq   = s * STRIP - 8 + 4 * q;           // frame col quad (4 floats)
    const int gcl4 = min(max(gq, 0), W - 4);          // clamped, 16B-aligned

    // consume geometry (identical to fused8's proven mapping)
    const int f   = s * STRIP - 8 + 2 * L;            // frame col (even)
    const bool cv = (f >= 0) && (f < W);
    const bool st = (L >= 4) && (L <= 59) && (f < W);

    const float* Ib = I + (size_t)b * CH * H * W;
    float* outb = out + (size_t)b * H * W;

    // chunk k: rows j = 8k..8k+7 (j>77 staged clamped, never consumed).
    // 24 (row,ch) pairs -> 12 width-16 instrs; wave w issues m = 3w..3w+2.
    auto stage = [&](int k) {
        const int slot = k & 3;
        #pragma unroll
        for (int i = 0; i < 3; ++i) {
            const int m  = 3 * w + i;                 // wave-uniform
            const int p  = 2 * m + g;                 // per-lane pair
            const int ch = p % 3;
            const int jr = p / 3;
            const int j  = 8 * k + jr;
            const int y  = min(max(Y0 - PAD + j, 0), H - 1);
            const float* gp = Ib + (size_t)ch * H * W + (size_t)y * W + gcl4;
            float* lp = &raw[slot * SLOT_F + m * 256];    // uniform base; HW adds lane*16
            __builtin_amdgcn_global_load_lds(
                (const __attribute__((address_space(1))) void*)gp,
                (__attribute__((address_space(3))) void*)lp,
                16, 0, 0);
        }
    };

    // h-min of one staged row: 3-ch min + INF mask + 15-wide shuffle net
    auto hrowL = [&](int slot, int jr, int j) -> float2 {
        const int fb = slot * SLOT_F + jr * 384 + 2 * L;  // pair (jr*3+ch) at p*128 floats
        const float2 A  = *(const float2*)&raw[fb];
        const float2 Bv = *(const float2*)&raw[fb + 128];
        const float2 Cv = *(const float2*)&raw[fb + 256];
        float2 d = min2(min2(A, Bv), Cv);
        const int gy = Y0 - PAD + j;
        const bool bad = (gy < 0) || (gy >= H) || !cv;
        d.x = bad ? INFINITY : d.x;                   // select, not branch
        d.y = bad ? INFINITY : d.y;
        const float pm = fminf(d.x, d.y);
        const float t2 = fminf(pm, __shfl_down(pm, 1));
        const float t4 = fminf(t2, __shfl_down(t2, 2));
        const float q7 = fminf(t4, __shfl_up(t4, 3)); // cols f-6..f+7
        float2 wv;
        wv.x = fminf(q7, __shfl_up(d.y, 4));          // + col f-7
        wv.y = fminf(q7, __shfl_down(d.x, 4));        // + col f+8
        return wv;
    };

    float2 hbuf[15];                                  // rows t=0..14, then suffix mins
    float2 obuf[16];                                  // deferred output rows
    float2 R;
    R.x = INFINITY; R.y = INFINITY;

    stage(0);
    stage(1);

    #pragma unroll
    for (int k = 0; k < NCHK; ++k) {
        if (k + 2 < NCHK) stage(k + 2);
        // counted wait: own outstanding loads after issue = 3*(chunks ahead)
        if (k < 8)       asm volatile("s_waitcnt vmcnt(6)" ::: "memory");
        else if (k == 8) asm volatile("s_waitcnt vmcnt(3)" ::: "memory");
        else             asm volatile("s_waitcnt vmcnt(0)" ::: "memory");
        __builtin_amdgcn_sched_barrier(0);
        __builtin_amdgcn_s_barrier();                 // raw barrier: no vmcnt(0) drain
        __builtin_amdgcn_sched_barrier(0);

        const int slot = k & 3;
        // wave w consumes its rows t = j - 16w (0..29) from chunks k = 2w+e
        const int e = k - 2 * w;                      // wave-uniform branch
        if (e == 0) {
            #pragma unroll
            for (int t = 0; t < 8; ++t)
                hbuf[t] = hrowL(slot, t, 16 * w + t);
        } else if (e == 1) {
            #pragma unroll
            for (int t = 8; t < 16; ++t) {
                const float2 h = hrowL(slot, t - 8, 16 * w + t);
                if (t < 14) {
                    hbuf[t] = h;
                } else if (t == 14) {
                    hbuf[14] = h;                     // rows 0..14 buffered
                    #pragma unroll
                    for (int u = 13; u >= 0; --u)     // in-place suffix mins
                        hbuf[u] = min2(hbuf[u], hbuf[u + 1]);
                    obuf[0] = hbuf[0];                // out r=0 = min(t=0..14)
                } else {                              // t == 15
                    R = h;                            // prefix from t=15
                    obuf[1] = min2(hbuf[1], R);
                }
            }
        } else if (e == 2) {
            #pragma unroll
            for (int t = 16; t < 24; ++t) {
                const float2 h = hrowL(slot, t - 16, 16 * w + t);
                R = min2(R, h);
                obuf[t - 14] = min2(hbuf[t - 14], R);
            }
        } else if (e == 3) {
            #pragma unroll
            for (int t = 24; t < 30; ++t) {
                const float2 h = hrowL(slot, t - 24, 16 * w + t);
                R = min2(R, h);
                if (t < 29) obuf[t - 14] = min2(hbuf[t - 14], R);
                else        obuf[15] = R;             // out r=15 = min(t=15..29)
            }
        }
    }

    if (st) {
        #pragma unroll
        for (int r = 0; r < 16; ++r)
            *(float2*)(outb + (size_t)(Y0 + 16 * w + r) * W + f) = obuf[r];
    }
}

extern "C" void kernel_launch(void* const* d_in, const int* in_sizes, int n_in,
                              void* d_out, int out_size, void* d_ws, size_t ws_size,
                              hipStream_t stream) {
    const float* I = (const float*)d_in[0];
    // d_in[1] is k == 15, hard-coded (KWIN/PAD)
    float* out = (float*)d_out;
    dcp_dma1<<<dim3(NBLK), dim3(256), 0, stream>>>(I, out);
}

// Round 6
// 160.626 us; speedup vs baseline: 1.0399x; 1.0399x over previous
//
#include <hip/hip_runtime.h>
#include <math.h>

#define BATCH  32
#define CH     3
#define H      512
#define W      512
#define KWIN   15
#define PAD    7
#define TB     64                 // output rows per BLOCK (4 waves x 16 rows)
#define NR     (TB + KWIN - 1)    // 78 staged h-min rows per block
#define STRIP  112                // output cols per block (frame = 128)
#define NSTRIP 5
#define LROW   112                // floats per LDS h-row
#define NBLK   (BATCH * (H / TB) * NSTRIP)   // 1280

typedef float vf2 __attribute__((ext_vector_type(2)));

static __device__ __forceinline__ float2 min2(float2 a, float2 b) {
    float2 r;
    r.x = fminf(a.x, b.x);
    r.y = fminf(a.y, b.y);
    return r;
}

// R21: LAST single-variable lever — load cache policy. Structure is dcp_lds1
// verbatim (measured 159.76 bench / ~55 us kernel, lowest issued bytes
// 153 MB), with the 3 streaming channel loads switched to NON-TEMPORAL
// (__builtin_nontemporal_load -> nt bit: no/evict-first allocation).
// Rationale: 9 structural changes (depth, TLP, occupancy, instr count,
// b128, -34% issued bytes, XCD swizzle, DMA-to-LDS path) are ALL neutral at
// ~2.7 TB/s delivered, yet m13's float4 copy streams 6.29 TB/s through the
// SAME TCP path — so the ceiling is not a hard per-CU miss cap. The one
// never-varied policy difference: our loads allocate in L1/L2 and mixed
// hit-traffic + partial-line stores share the same concurrency/allocation
// budget as the cold miss stream. nt removes the allocation side.
// Predict: if policy is the drag, kernel 55 -> ~40 us, bench ~145; FETCH
// ~99 MB unchanged. Kill: bench >= 157 -> declare roofline (147 MB
// compulsory / 2.7 TB/s windowed-mixed ceiling ~= 55 us, invariant under
// 9 orthogonal structures).
// Falsified (do not retry): b128 (R17), issued-bytes cut (R18), XCD swizzle
// (R19), global_load_lds DMA (R20: +7 us), DEPTH/TLP, __launch_bounds__,
// global two-pass, dynamic reg indexing.
__global__ void dcp_lds3(const float* __restrict__ I, float* __restrict__ out) {
    __shared__ float hl[NR][LROW];                    // 34944 B

    const int w   = threadIdx.x >> 6;                 // wave 0..3
    const int L   = threadIdx.x & 63;
    const int bid = blockIdx.x;
    const int s   = bid % NSTRIP;
    const int rg  = (bid / NSTRIP) % (H / TB);        // 0..7
    const int b   = bid / (NSTRIP * (H / TB));
    const int Y0  = rg * TB;                          // first output row of block

    // ---- stage-phase lane geometry (proven fused8 mapping) ----
    const int f   = s * STRIP - 8 + 2 * L;            // frame col (even)
    const int cl  = min(max(f, 0), W - 2);            // clamped, 8B-aligned
    const bool cv = (f >= 0) && (f < W);
    const bool sw = (L >= 4) && (L <= 59);            // lane writes LDS cols 2L-8, 2L-7

    const float* base = I + (size_t)b * CH * H * W + cl;
    float* outb = out + (size_t)b * H * W;

    auto ntload2 = [](const float* p) -> float2 {
        const vf2 t = __builtin_nontemporal_load((const vf2*)p);
        float2 r; r.x = t.x; r.y = t.y; return r;
    };

    auto ldrow = [&](int j, float2& A, float2& B, float2& C) {
        const int gc = min(max(Y0 - PAD + j, 0), H - 1);
        const float* p = base + (size_t)gc * W;
        A = ntload2(p);
        B = ntload2(p + (size_t)H * W);
        C = ntload2(p + (size_t)2 * H * W);
    };

    // channel-min + 15-wide horizontal min (verified shuffle net)
    auto hrow = [&](int j, float2 A, float2 B, float2 C) -> float2 {
        const int g = Y0 - PAD + j;                   // global input row
        float2 d = min2(min2(A, B), C);
        const bool pad = (g < 0) || (g >= H) || !cv;
        d.x = pad ? INFINITY : d.x;                   // select, not branch
        d.y = pad ? INFINITY : d.y;
        const float pm = fminf(d.x, d.y);             // pair min (cols f,f+1)
        const float t2 = fminf(pm, __shfl_down(pm, 1));
        const float t4 = fminf(t2, __shfl_down(t2, 2));
        const float q7 = fminf(t4, __shfl_up(t4, 3)); // cols f-6..f+7
        float2 wv;
        wv.x = fminf(q7, __shfl_up(d.y, 4));          // + col f-7
        wv.y = fminf(q7, __shfl_down(d.x, 4));        // + col f+8
        return wv;
    };

    // ---- phase 1: stage 78 h-min rows, round-robin rows across 4 waves ----
    float2 Ab[4], Bb[4], Cb[4];
    #pragma unroll
    for (int t = 0; t < 4; ++t)
        ldrow(w + 4 * t, Ab[t], Bb[t], Cb[t]);        // j <= 15 < NR always

    #pragma unroll
    for (int t = 0; t < 20; ++t) {
        const int j = w + 4 * t;
        if (j < NR) {                                 // wave-uniform branch
            const int sl = t & 3;                     // constant after unroll
            const float2 hv = hrow(j, Ab[sl], Bb[sl], Cb[sl]);
            const int j2 = w + 4 * (t + 4);
            if (t + 4 < 20 && j2 < NR)
                ldrow(j2, Ab[sl], Bb[sl], Cb[sl]);
            if (sw)
                *(float2*)&hl[j][2 * L - 8] = hv;     // 2-way bank alias: free
        }
    }
    __syncthreads();

    // ---- phase 2: vertical 15-min van Herk from LDS; wave w -> rows Y0+16w.. ----
    const int lw = 16 * w;                            // local base row
    const int c  = min(2 * L, LROW - 2);              // local col (clamp lanes 56..63)
    const int oc = s * STRIP + 2 * L;                 // global out col
    const bool st = (2 * L < LROW) && (oc < W);       // valid store lanes

    auto seqrow = [](int q) { return q < KWIN ? KWIN + q : 29 - q; };
    auto rdrow  = [&](int lr) -> float2 {
        return *(const float2*)&hl[lw + lr][c];
    };

    float2 P[KWIN];
    float2 U;
    #pragma unroll
    for (int q = 0; q < 30; ++q) {
        const int lr = seqrow(q);                     // 15..29 then 14..0
        const float2 h = rdrow(lr);
        if (q == 0) {
            P[0] = h;
        } else if (q < KWIN) {
            P[q] = min2(P[q - 1], h);                 // P[q] = min(lr=15..15+q)
            if (q == KWIN - 1 && st)
                *(float2*)(outb + (size_t)(Y0 + lw + 15) * W + oc) = P[KWIN - 1];
        } else if (q == KWIN) {                       // lr = 14 -> out row 14
            U = h;
            if (st) *(float2*)(outb + (size_t)(Y0 + lw + 14) * W + oc) = min2(U, P[13]);
        } else if (q < 29) {                          // out rows 13..1
            const int r = 29 - q;
            U = min2(U, h);
            if (st) *(float2*)(outb + (size_t)(Y0 + lw + r) * W + oc) = min2(U, P[r - 1]);
        } else {                                      // out row 0
            U = min2(U, h);
            if (st) *(float2*)(outb + (size_t)(Y0 + lw) * W + oc) = U;
        }
    }
}

extern "C" void kernel_launch(void* const* d_in, const int* in_sizes, int n_in,
                              void* d_out, int out_size, void* d_ws, size_t ws_size,
                              hipStream_t stream) {
    const float* I = (const float*)d_in[0];
    // d_in[1] is k == 15, hard-coded (KWIN/PAD)
    float* out = (float*)d_out;
    dcp_lds3<<<dim3(NBLK), dim3(256), 0, stream>>>(I, out);
}